// Round 3
// baseline (304.677 us; speedup 1.0000x reference)
//
#include <hip/hip_runtime.h>
#include <math.h>

#define NPOS 9216   // 96*96

using half8  = __attribute__((ext_vector_type(8))) _Float16;
using f32x4  = __attribute__((ext_vector_type(4))) float;
using f32x16 = __attribute__((ext_vector_type(16))) float;

// ---- workspace layout (byte offsets, all 16B aligned) ----
#define OFF_FEATT 0u         // 98*98*64 f16 = 1,229,312 B (zero-padded border)
#define OFF_A0    1229312u   // 9216*256 f16 = 4,718,592 B
#define OFF_WF32  5947904u   // 3*65536 f16 (hidden B-frags, 32x32x16)
#define OFF_WF4   6341120u   // 4096 f16 (w4 B-frags, 16x16x32, padded to 16 cols)
#define OFF_WB    6349312u   // 9*2*16*64*8 f16 (a0 B-frags, 16x16x32)

#define NB_FEAT 2401   // 9604 positions / 4 per block
#define NB_PA   768    // 3*65536 / 256
#define NB_PW4  16     // 4096 / 256
#define NB_PB   576    // 147456 / 256

// ---------------------------------------------------------------------------
// Setup: (a) conv encoder -> zero-padded position-major f16 featT[98][98][64]
//        (b) pack w1/w2/w3 into 32x32x16 B-fragment order
//        (c) pack w4 into 16x16x32 B-fragment order (cols padded 3->16)
//        (d) pack w0's first 576 rows into 16x16x32 B-frags per unfold tap t9
// ---------------------------------------------------------------------------
__global__ __launch_bounds__(256) void setup_kernel(
    const float* __restrict__ inp, const float* __restrict__ enc_w,
    const float* __restrict__ enc_b, const float* __restrict__ w0,
    const float* __restrict__ w1, const float* __restrict__ w2,
    const float* __restrict__ w3, const float* __restrict__ w4,
    _Float16* __restrict__ featT, _Float16* __restrict__ wf32,
    _Float16* __restrict__ wf4, _Float16* __restrict__ wB)
{
    int blk = blockIdx.x;
    const int t = threadIdx.x;

    if (blk < NB_FEAT) {                       // conv -> featT (padded)
        int pp = blk * 4 + (t >> 6);           // 0..9603
        int c  = t & 63;
        int py = pp / 98, px = pp - py * 98;
        float acc = 0.0f;
        if (py >= 1 && py <= 96 && px >= 1 && px <= 96) {
            int y = py - 1, x = px - 1;
            acc = enc_b[c];
            #pragma unroll
            for (int cin = 0; cin < 3; ++cin) {
                #pragma unroll
                for (int ky = 0; ky < 3; ++ky) {
                    int yy = y + ky - 1;
                    if (yy < 0 || yy >= 96) continue;
                    #pragma unroll
                    for (int kx = 0; kx < 3; ++kx) {
                        int xx = x + kx - 1;
                        if (xx < 0 || xx >= 96) continue;
                        acc = fmaf(inp[cin * NPOS + yy * 96 + xx],
                                   enc_w[c * 27 + cin * 9 + ky * 3 + kx], acc);
                    }
                }
            }
        }
        featT[pp * 64 + c] = (_Float16)acc;
        return;
    }
    blk -= NB_FEAT;
    if (blk < NB_PA) {                         // hidden weights, 32x32x16 B-frag
        int idx = blk * 256 + t;               // 0..196607
        int l = idx >> 16;
        int r = idx & 65535;
        int j    = r & 7;
        int lane = (r >> 3) & 63;
        int nt32 = (r >> 9) & 7;
        int ks   = r >> 12;                    // 0..15
        int n = nt32 * 32 + (lane & 31);
        int k = ks * 16 + ((lane >> 5) << 3) + j;
        const float* W = (l == 0) ? w1 : (l == 1) ? w2 : w3;
        wf32[idx] = (_Float16)W[k * 256 + n];
        return;
    }
    blk -= NB_PA;
    if (blk < NB_PW4) {                        // w4, 16x16x32 B-frag
        int idx = blk * 256 + t;               // 0..4095
        int j    = idx & 7;
        int lane = (idx >> 3) & 63;
        int ks   = idx >> 9;                   // 0..7
        int n = lane & 15;
        int k = ks * 32 + ((lane >> 4) << 3) + j;
        wf4[idx] = (n < 3) ? (_Float16)w4[k * 3 + n] : (_Float16)0.0f;
        return;
    }
    blk -= NB_PW4;
    {                                          // w0 taps, 16x16x32 B-frag (K=64 per tap)
        int idx = blk * 256 + t;               // 0..147455
        int j    = idx & 7;
        int lane = (idx >> 3) & 63;
        int ntB  = (idx >> 9) & 15;
        int ks   = (idx >> 13) & 1;
        int t9   = idx >> 14;                  // 0..8
        int c = ks * 32 + ((lane >> 4) << 3) + j;
        int n = ntB * 16 + (lane & 15);
        wB[idx] = (_Float16)w0[(c * 9 + t9) * 256 + n];
    }
}

// ---------------------------------------------------------------------------
// a0 via MFMA: A0[pos][o] = b0[o] + sum_t9 featT(pos shifted by t9) @ w0-tap-t9
// 144 blocks x 256 threads; each wave owns one 16-row tile x 256 cols.
// ---------------------------------------------------------------------------
__global__ __launch_bounds__(256) void a0_mfma(const _Float16* __restrict__ featT,
                                               const _Float16* __restrict__ wB,
                                               const float* __restrict__ b0,
                                               _Float16* __restrict__ A0)
{
    const int lane = threadIdx.x & 63;
    const int tile = blockIdx.x * 4 + (threadIdx.x >> 6);   // 0..575
    const int l15  = lane & 15;
    const int l4   = lane >> 4;
    int r = tile * 16 + l15;
    int y = r / 96, x = r - y * 96;

    f32x4 acc[16];
    #pragma unroll
    for (int nt = 0; nt < 16; ++nt) acc[nt] = (f32x4){0.f, 0.f, 0.f, 0.f};

    #pragma unroll
    for (int t9 = 0; t9 < 9; ++t9) {
        int ki = t9 / 3, kj = t9 - ki * 3;
        const _Float16* ap = featT + ((y + ki) * 98 + (x + kj)) * 64 + l4 * 8;
        #pragma unroll
        for (int ks = 0; ks < 2; ++ks) {
            half8 a = *(const half8*)(ap + ks * 32);
            const _Float16* bp = wB + ((t9 * 2 + ks) * 16 * 64 + lane) * 8;
            #pragma unroll
            for (int nt = 0; nt < 16; ++nt) {
                half8 b = *(const half8*)(bp + nt * 512);
                acc[nt] = __builtin_amdgcn_mfma_f32_16x16x32_f16(a, b, acc[nt], 0, 0, 0);
            }
        }
    }
    int rb = tile * 16 + l4 * 4;
    #pragma unroll
    for (int nt = 0; nt < 16; ++nt) {
        float bb = b0[nt * 16 + l15];
        #pragma unroll
        for (int i = 0; i < 4; ++i)
            A0[(rb + i) * 256 + nt * 16 + l15] = (_Float16)(acc[nt][i] + bb);
    }
}

// ---------------------------------------------------------------------------
// Fused MLP: 128 rows (= 32 queries x 4 ensemble) per block, 512 threads.
// Hidden layers on mfma_f32_32x32x16_f16; wave (wm,wn) owns 64x64 out tile.
// ---------------------------------------------------------------------------
__device__ __forceinline__ void hidden32(_Float16 (*h)[264],
                                         const _Float16* __restrict__ W,
                                         const float* __restrict__ bias,
                                         int wm, int wn, int lane)
{
    const int l31 = lane & 31;
    const int l5  = lane >> 5;
    f32x16 a00 = {}, a01 = {}, a10 = {}, a11 = {};
    #pragma unroll
    for (int ks = 0; ks < 16; ++ks) {
        half8 Av0 = *(const half8*)&h[wm * 64 + l31][ks * 16 + l5 * 8];
        half8 Av1 = *(const half8*)&h[wm * 64 + 32 + l31][ks * 16 + l5 * 8];
        const _Float16* bp = W + (ks * 8 + wn * 2) * 512 + lane * 8;
        half8 Bv0 = *(const half8*)bp;
        half8 Bv1 = *(const half8*)(bp + 512);
        a00 = __builtin_amdgcn_mfma_f32_32x32x16_f16(Av0, Bv0, a00, 0, 0, 0);
        a01 = __builtin_amdgcn_mfma_f32_32x32x16_f16(Av0, Bv1, a01, 0, 0, 0);
        a10 = __builtin_amdgcn_mfma_f32_32x32x16_f16(Av1, Bv0, a10, 0, 0, 0);
        a11 = __builtin_amdgcn_mfma_f32_32x32x16_f16(Av1, Bv1, a11, 0, 0, 0);
    }
    __syncthreads();   // all reads of h done before overwrite
    float bv0 = bias[wn * 64 + l31];
    float bv1 = bias[wn * 64 + 32 + l31];
    #pragma unroll
    for (int reg = 0; reg < 16; ++reg) {
        int rr = (reg & 3) + ((reg >> 2) << 3) + (l5 << 2);
        int r0 = wm * 64 + rr;
        int c0 = wn * 64 + l31;
        h[r0][c0]           = (_Float16)fmaxf(a00[reg] + bv0, 0.0f);
        h[r0][c0 + 32]      = (_Float16)fmaxf(a01[reg] + bv1, 0.0f);
        h[r0 + 32][c0]      = (_Float16)fmaxf(a10[reg] + bv0, 0.0f);
        h[r0 + 32][c0 + 32] = (_Float16)fmaxf(a11[reg] + bv1, 0.0f);
    }
    __syncthreads();
}

__global__ __launch_bounds__(512, 4) void fused_kernel(
    const _Float16* __restrict__ A0, const float* __restrict__ coord,
    const float* __restrict__ cell, const float* __restrict__ w0,
    const float* __restrict__ b1, const float* __restrict__ b2,
    const float* __restrict__ b3, const float* __restrict__ b4,
    const _Float16* __restrict__ wf32, const _Float16* __restrict__ wf4,
    float* __restrict__ out)
{
    __shared__ _Float16 h[128][264];
    __shared__ float pred[128][4];
    __shared__ float s_rel0[128], s_rel1[128], s_rc0[128], s_rc1[128], s_area[128];
    __shared__ int   s_pos[128];

    const int t   = threadIdx.x;
    const int blk = blockIdx.x;

    if (t < 128) {
        int r = blk * 128 + t;
        int q = r >> 2;
        int j = r & 3;                         // (vx,vy): 0:(-,-) 1:(-,+) 2:(+,-) 3:(+,+)
        float vx = (j & 2) ? 1.0f : -1.0f;
        float vy = (j & 1) ? 1.0f : -1.0f;
        float c0 = coord[q * 2 + 0];
        float c1 = coord[q * 2 + 1];
        const float rr  = 1.0f / 96.0f;
        const float bnd = 1.0f - 1e-6f;
        float sc0 = fminf(fmaxf(fmaf(vx, rr, c0) + 1e-6f, -bnd), bnd);
        float sc1 = fminf(fmaxf(fmaf(vy, rr, c1) + 1e-6f, -bnd), bnd);
        float fy = (sc0 + 1.0f) * 48.0f - 0.5f;
        float fx = (sc1 + 1.0f) * 48.0f - 0.5f;
        int iy = (int)rintf(fy); iy = iy < 0 ? 0 : (iy > 95 ? 95 : iy);
        int ix = (int)rintf(fx); ix = ix < 0 ? 0 : (ix > 95 ? 95 : ix);
        float fcy = -1.0f + (2.0f * (float)iy + 1.0f) / 96.0f;
        float fcx = -1.0f + (2.0f * (float)ix + 1.0f) / 96.0f;
        float rel0 = (c0 - fcy) * 96.0f;
        float rel1 = (c1 - fcx) * 96.0f;
        s_pos[t]  = iy * 96 + ix;
        s_rel0[t] = rel0;
        s_rel1[t] = rel1;
        s_rc0[t]  = cell[q * 2 + 0] * 96.0f;
        s_rc1[t]  = cell[q * 2 + 1] * 96.0f;
        s_area[t] = fabsf(rel0 * rel1) + 1e-9f;
    }
    __syncthreads();

    // ---- layer 0: h = relu(A0[pos] + rel0*w0[576] + rel1*w0[577] + rc*w0[578..579])
    {
        int col = t & 255;
        int m0  = (t >> 8) * 64;
        float wa = w0[576 * 256 + col];
        float wb = w0[577 * 256 + col];
        float wc = w0[578 * 256 + col];
        float wd = w0[579 * 256 + col];
        #pragma unroll 4
        for (int mm = 0; mm < 64; ++mm) {
            int m = m0 + mm;
            float v = (float)A0[s_pos[m] * 256 + col];
            v = fmaf(s_rel0[m], wa, v);
            v = fmaf(s_rel1[m], wb, v);
            v = fmaf(s_rc0[m], wc, v);
            v = fmaf(s_rc1[m], wd, v);
            h[m][col] = (_Float16)fmaxf(v, 0.0f);
        }
    }
    __syncthreads();

    const int wave = t >> 6;
    const int lane = t & 63;
    const int wm = wave >> 2;
    const int wn = wave & 3;

    hidden32(h, wf32,             b1, wm, wn, lane);
    hidden32(h, wf32 + 65536,     b2, wm, wn, lane);
    hidden32(h, wf32 + 2 * 65536, b3, wm, wn, lane);

    // ---- final layer 256 -> 3 via 16x16x32 MFMA; wave = 16-row tile
    {
        const int l15 = lane & 15;
        const int l4  = lane >> 4;
        f32x4 acc = (f32x4){0.f, 0.f, 0.f, 0.f};
        #pragma unroll
        for (int ks = 0; ks < 8; ++ks) {
            half8 a = *(const half8*)&h[wave * 16 + l15][ks * 32 + l4 * 8];
            half8 b = *(const half8*)&wf4[(ks * 64 + lane) * 8];
            acc = __builtin_amdgcn_mfma_f32_16x16x32_f16(a, b, acc, 0, 0, 0);
        }
        if (l15 < 3) {
            float bv = b4[l15];
            #pragma unroll
            for (int i = 0; i < 4; ++i)
                pred[wave * 16 + l4 * 4 + i][l15] = acc[i] + bv;
        }
    }
    __syncthreads();

    // ---- local-ensemble combine (diagonal area swap), 32 queries per block
    if (t < 96) {
        int ql = t / 3;
        int o  = t - ql * 3;
        int mb = ql * 4;
        float a0 = s_area[mb + 0];
        float a1 = s_area[mb + 1];
        float a2 = s_area[mb + 2];
        float a3 = s_area[mb + 3];
        float tot = a0 + a1 + a2 + a3;
        float rv = pred[mb + 0][o] * a3 + pred[mb + 1][o] * a2 +
                   pred[mb + 2][o] * a1 + pred[mb + 3][o] * a0;
        out[(blk * 32 + ql) * 3 + o] = rv / tot;
    }
}

// ---------------------------------------------------------------------------
extern "C" void kernel_launch(void* const* d_in, const int* in_sizes, int n_in,
                              void* d_out, int out_size, void* d_ws, size_t ws_size,
                              hipStream_t stream)
{
    (void)in_sizes; (void)n_in; (void)out_size; (void)ws_size;
    const float* inp   = (const float*)d_in[0];
    const float* coord = (const float*)d_in[1];
    const float* cell  = (const float*)d_in[2];
    const float* enc_w = (const float*)d_in[3];
    const float* enc_b = (const float*)d_in[4];
    const float* w0 = (const float*)d_in[5];
    const float* b0 = (const float*)d_in[6];
    const float* w1 = (const float*)d_in[7];
    const float* b1 = (const float*)d_in[8];
    const float* w2 = (const float*)d_in[9];
    const float* b2 = (const float*)d_in[10];
    const float* w3 = (const float*)d_in[11];
    const float* b3 = (const float*)d_in[12];
    const float* w4 = (const float*)d_in[13];
    const float* b4 = (const float*)d_in[14];
    float* outp = (float*)d_out;

    char* ws = (char*)d_ws;
    _Float16* featT = (_Float16*)(ws + OFF_FEATT);
    _Float16* A0    = (_Float16*)(ws + OFF_A0);
    _Float16* wf32  = (_Float16*)(ws + OFF_WF32);
    _Float16* wf4   = (_Float16*)(ws + OFF_WF4);
    _Float16* wB    = (_Float16*)(ws + OFF_WB);

    setup_kernel<<<dim3(NB_FEAT + NB_PA + NB_PW4 + NB_PB), dim3(256), 0, stream>>>(
        inp, enc_w, enc_b, w0, w1, w2, w3, w4, featT, wf32, wf4, wB);
    a0_mfma<<<dim3(144), dim3(256), 0, stream>>>(featT, wB, b0, A0);
    fused_kernel<<<dim3(2048), dim3(512), 0, stream>>>(A0, coord, cell, w0,
                                                       b1, b2, b3, b4, wf32, wf4, outp);
}

// Round 4
// 296.963 us; speedup vs baseline: 1.0260x; 1.0260x over previous
//
#include <hip/hip_runtime.h>
#include <math.h>

#define NPOS 9216   // 96*96

using half8  = __attribute__((ext_vector_type(8))) _Float16;
using f32x4  = __attribute__((ext_vector_type(4))) float;
using f32x16 = __attribute__((ext_vector_type(16))) float;

// ---- workspace layout (byte offsets, all 16B aligned) ----
#define OFF_FEATT 0u         // 98*98*64 f16 = 1,229,312 B (zero-padded border)
#define OFF_A0    1229312u   // 9216*256 f16 = 4,718,592 B
#define OFF_WF32  5947904u   // 3*65536 f16 (hidden B-frags, 32x32x16)
#define OFF_WF4   6341120u   // 4096 f16 (w4 B-frags, 16x16x32, padded to 16 cols)
#define OFF_WB    6349312u   // 9*2*16*64*8 f16 (a0 B-frags, 16x16x32)

#define NB_FEAT 2401   // 9604 positions / 4 per block
#define NB_PA   768    // 3*65536 / 256
#define NB_PW4  16     // 4096 / 256
#define NB_PB   576    // 147456 / 256

// raw barrier: LDS-ordered, but does NOT drain vmcnt (prefetch stays in flight)
#define BAR() do { asm volatile("s_waitcnt lgkmcnt(0)" ::: "memory"); \
                   __builtin_amdgcn_s_barrier();                      \
                   asm volatile("" ::: "memory"); } while (0)

// ---------------------------------------------------------------------------
// Setup: (a) conv encoder -> zero-padded position-major f16 featT[98][98][64]
//        (b) pack w1/w2/w3 into 32x32x16 B-fragment order
//        (c) pack w4 into 16x16x32 B-fragment order (cols padded 3->16)
//        (d) pack w0's first 576 rows into 16x16x32 B-frags per unfold tap t9
// ---------------------------------------------------------------------------
__global__ __launch_bounds__(256) void setup_kernel(
    const float* __restrict__ inp, const float* __restrict__ enc_w,
    const float* __restrict__ enc_b, const float* __restrict__ w0,
    const float* __restrict__ w1, const float* __restrict__ w2,
    const float* __restrict__ w3, const float* __restrict__ w4,
    _Float16* __restrict__ featT, _Float16* __restrict__ wf32,
    _Float16* __restrict__ wf4, _Float16* __restrict__ wB)
{
    int blk = blockIdx.x;
    const int t = threadIdx.x;

    if (blk < NB_FEAT) {                       // conv -> featT (padded)
        int pp = blk * 4 + (t >> 6);           // 0..9603
        int c  = t & 63;
        int py = pp / 98, px = pp - py * 98;
        float acc = 0.0f;
        if (py >= 1 && py <= 96 && px >= 1 && px <= 96) {
            int y = py - 1, x = px - 1;
            acc = enc_b[c];
            #pragma unroll
            for (int cin = 0; cin < 3; ++cin) {
                #pragma unroll
                for (int ky = 0; ky < 3; ++ky) {
                    int yy = y + ky - 1;
                    if (yy < 0 || yy >= 96) continue;
                    #pragma unroll
                    for (int kx = 0; kx < 3; ++kx) {
                        int xx = x + kx - 1;
                        if (xx < 0 || xx >= 96) continue;
                        acc = fmaf(inp[cin * NPOS + yy * 96 + xx],
                                   enc_w[c * 27 + cin * 9 + ky * 3 + kx], acc);
                    }
                }
            }
        }
        featT[pp * 64 + c] = (_Float16)acc;
        return;
    }
    blk -= NB_FEAT;
    if (blk < NB_PA) {                         // hidden weights, 32x32x16 B-frag
        int idx = blk * 256 + t;               // 0..196607
        int l = idx >> 16;
        int r = idx & 65535;
        int j    = r & 7;
        int lane = (r >> 3) & 63;
        int nt32 = (r >> 9) & 7;
        int ks   = r >> 12;                    // 0..15
        int n = nt32 * 32 + (lane & 31);
        int k = ks * 16 + ((lane >> 5) << 3) + j;
        const float* W = (l == 0) ? w1 : (l == 1) ? w2 : w3;
        wf32[idx] = (_Float16)W[k * 256 + n];
        return;
    }
    blk -= NB_PA;
    if (blk < NB_PW4) {                        // w4, 16x16x32 B-frag
        int idx = blk * 256 + t;               // 0..4095
        int j    = idx & 7;
        int lane = (idx >> 3) & 63;
        int ks   = idx >> 9;                   // 0..7
        int n = lane & 15;
        int k = ks * 32 + ((lane >> 4) << 3) + j;
        wf4[idx] = (n < 3) ? (_Float16)w4[k * 3 + n] : (_Float16)0.0f;
        return;
    }
    blk -= NB_PW4;
    {                                          // w0 taps, 16x16x32 B-frag (K=64 per tap)
        int idx = blk * 256 + t;               // 0..147455
        int j    = idx & 7;
        int lane = (idx >> 3) & 63;
        int ntB  = (idx >> 9) & 15;
        int ks   = (idx >> 13) & 1;
        int t9   = idx >> 14;                  // 0..8
        int c = ks * 32 + ((lane >> 4) << 3) + j;
        int n = ntB * 16 + (lane & 15);
        wB[idx] = (_Float16)w0[(c * 9 + t9) * 256 + n];
    }
}

// ---------------------------------------------------------------------------
// a0 via MFMA: A0[pos][o] = b0[o] + sum_t9 featT(pos shifted by t9) @ w0-tap-t9
// ---------------------------------------------------------------------------
__global__ __launch_bounds__(256) void a0_mfma(const _Float16* __restrict__ featT,
                                               const _Float16* __restrict__ wB,
                                               const float* __restrict__ b0,
                                               _Float16* __restrict__ A0)
{
    const int lane = threadIdx.x & 63;
    const int tile = blockIdx.x * 4 + (threadIdx.x >> 6);   // 0..575
    const int l15  = lane & 15;
    const int l4   = lane >> 4;
    int r = tile * 16 + l15;
    int y = r / 96, x = r - y * 96;

    f32x4 acc[16];
    #pragma unroll
    for (int nt = 0; nt < 16; ++nt) acc[nt] = (f32x4){0.f, 0.f, 0.f, 0.f};

    #pragma unroll
    for (int t9 = 0; t9 < 9; ++t9) {
        int ki = t9 / 3, kj = t9 - ki * 3;
        const _Float16* ap = featT + ((y + ki) * 98 + (x + kj)) * 64 + l4 * 8;
        #pragma unroll
        for (int ks = 0; ks < 2; ++ks) {
            half8 a = *(const half8*)(ap + ks * 32);
            const _Float16* bp = wB + ((t9 * 2 + ks) * 16 * 64 + lane) * 8;
            #pragma unroll
            for (int nt = 0; nt < 16; ++nt) {
                half8 b = *(const half8*)(bp + nt * 512);
                acc[nt] = __builtin_amdgcn_mfma_f32_16x16x32_f16(a, b, acc[nt], 0, 0, 0);
            }
        }
    }
    int rb = tile * 16 + l4 * 4;
    #pragma unroll
    for (int nt = 0; nt < 16; ++nt) {
        float bb = b0[nt * 16 + l15];
        #pragma unroll
        for (int i = 0; i < 4; ++i)
            A0[(rb + i) * 256 + nt * 16 + l15] = (_Float16)(acc[nt][i] + bb);
    }
}

// ---------------------------------------------------------------------------
// Hidden layer on 32x32x16 MFMA with cross-layer B prefetch.
// p0..p3 = this layer's ks=0,1 B-frags (preloaded). q0..q3 = next prefetch out.
// ---------------------------------------------------------------------------
__device__ __forceinline__ void hidden_layer32(
    _Float16 (*h)[264], const _Float16* __restrict__ W,
    const float* __restrict__ bias, const _Float16* __restrict__ Wpre,
    bool preIsFinal,
    half8 p0, half8 p1, half8 p2, half8 p3,
    half8& q0, half8& q1, half8& q2, half8& q3,
    int wm, int wn, int lane)
{
    const int l31 = lane & 31;
    const int l5  = lane >> 5;
    f32x16 a00 = {}, a01 = {}, a10 = {}, a11 = {};

    // ks = 0,1 from prefetched frags
    {
        half8 Av0 = *(const half8*)&h[wm * 64 + l31][l5 * 8];
        half8 Av1 = *(const half8*)&h[wm * 64 + 32 + l31][l5 * 8];
        a00 = __builtin_amdgcn_mfma_f32_32x32x16_f16(Av0, p0, a00, 0, 0, 0);
        a01 = __builtin_amdgcn_mfma_f32_32x32x16_f16(Av0, p1, a01, 0, 0, 0);
        a10 = __builtin_amdgcn_mfma_f32_32x32x16_f16(Av1, p0, a10, 0, 0, 0);
        a11 = __builtin_amdgcn_mfma_f32_32x32x16_f16(Av1, p1, a11, 0, 0, 0);
        Av0 = *(const half8*)&h[wm * 64 + l31][16 + l5 * 8];
        Av1 = *(const half8*)&h[wm * 64 + 32 + l31][16 + l5 * 8];
        a00 = __builtin_amdgcn_mfma_f32_32x32x16_f16(Av0, p2, a00, 0, 0, 0);
        a01 = __builtin_amdgcn_mfma_f32_32x32x16_f16(Av0, p3, a01, 0, 0, 0);
        a10 = __builtin_amdgcn_mfma_f32_32x32x16_f16(Av1, p2, a10, 0, 0, 0);
        a11 = __builtin_amdgcn_mfma_f32_32x32x16_f16(Av1, p3, a11, 0, 0, 0);
    }
    #pragma unroll
    for (int ks = 2; ks < 16; ++ks) {
        half8 Av0 = *(const half8*)&h[wm * 64 + l31][ks * 16 + l5 * 8];
        half8 Av1 = *(const half8*)&h[wm * 64 + 32 + l31][ks * 16 + l5 * 8];
        const _Float16* bp = W + (ks * 8 + wn * 2) * 512 + lane * 8;
        half8 Bv0 = *(const half8*)bp;
        half8 Bv1 = *(const half8*)(bp + 512);
        a00 = __builtin_amdgcn_mfma_f32_32x32x16_f16(Av0, Bv0, a00, 0, 0, 0);
        a01 = __builtin_amdgcn_mfma_f32_32x32x16_f16(Av0, Bv1, a01, 0, 0, 0);
        a10 = __builtin_amdgcn_mfma_f32_32x32x16_f16(Av1, Bv0, a10, 0, 0, 0);
        a11 = __builtin_amdgcn_mfma_f32_32x32x16_f16(Av1, Bv1, a11, 0, 0, 0);
    }

    // prefetch next layer's ks=0,1 (or final w4 ks=0..3); stays in flight across BAR
    if (preIsFinal) {
        q0 = *(const half8*)&Wpre[(0 * 64 + lane) * 8];
        q1 = *(const half8*)&Wpre[(1 * 64 + lane) * 8];
        q2 = *(const half8*)&Wpre[(2 * 64 + lane) * 8];
        q3 = *(const half8*)&Wpre[(3 * 64 + lane) * 8];
    } else {
        const _Float16* bp0 = Wpre + (wn * 2) * 512 + lane * 8;
        const _Float16* bp1 = Wpre + (8 + wn * 2) * 512 + lane * 8;
        q0 = *(const half8*)bp0;
        q1 = *(const half8*)(bp0 + 512);
        q2 = *(const half8*)bp1;
        q3 = *(const half8*)(bp1 + 512);
    }

    BAR();   // all reads of h done before overwrite
    float bv0 = bias[wn * 64 + l31];
    float bv1 = bias[wn * 64 + 32 + l31];
    #pragma unroll
    for (int reg = 0; reg < 16; ++reg) {
        int rr = (reg & 3) + ((reg >> 2) << 3) + (l5 << 2);
        int r0 = wm * 64 + rr;
        int c0 = wn * 64 + l31;
        h[r0][c0]           = (_Float16)fmaxf(a00[reg] + bv0, 0.0f);
        h[r0][c0 + 32]      = (_Float16)fmaxf(a01[reg] + bv1, 0.0f);
        h[r0 + 32][c0]      = (_Float16)fmaxf(a10[reg] + bv0, 0.0f);
        h[r0 + 32][c0 + 32] = (_Float16)fmaxf(a11[reg] + bv1, 0.0f);
    }
    BAR();   // h ready for next layer
}

__global__ __launch_bounds__(512, 4) void fused_kernel(
    const _Float16* __restrict__ A0, const float* __restrict__ coord,
    const float* __restrict__ cell, const float* __restrict__ w0,
    const float* __restrict__ b1, const float* __restrict__ b2,
    const float* __restrict__ b3, const float* __restrict__ b4,
    const _Float16* __restrict__ wf32, const _Float16* __restrict__ wf4,
    float* __restrict__ out)
{
    __shared__ _Float16 h[128][264];
    __shared__ float pred[128][4];
    __shared__ float s_rel0[128], s_rel1[128], s_rc0[128], s_rc1[128], s_area[128];
    __shared__ int   s_pos[128];

    const int t   = threadIdx.x;
    const int blk = blockIdx.x;

    if (t < 128) {
        int r = blk * 128 + t;
        int q = r >> 2;
        int j = r & 3;                         // (vx,vy): 0:(-,-) 1:(-,+) 2:(+,-) 3:(+,+)
        float vx = (j & 2) ? 1.0f : -1.0f;
        float vy = (j & 1) ? 1.0f : -1.0f;
        float c0 = coord[q * 2 + 0];
        float c1 = coord[q * 2 + 1];
        const float rr  = 1.0f / 96.0f;
        const float bnd = 1.0f - 1e-6f;
        float sc0 = fminf(fmaxf(fmaf(vx, rr, c0) + 1e-6f, -bnd), bnd);
        float sc1 = fminf(fmaxf(fmaf(vy, rr, c1) + 1e-6f, -bnd), bnd);
        float fy = (sc0 + 1.0f) * 48.0f - 0.5f;
        float fx = (sc1 + 1.0f) * 48.0f - 0.5f;
        int iy = (int)rintf(fy); iy = iy < 0 ? 0 : (iy > 95 ? 95 : iy);
        int ix = (int)rintf(fx); ix = ix < 0 ? 0 : (ix > 95 ? 95 : ix);
        float fcy = -1.0f + (2.0f * (float)iy + 1.0f) / 96.0f;
        float fcx = -1.0f + (2.0f * (float)ix + 1.0f) / 96.0f;
        float rel0 = (c0 - fcy) * 96.0f;
        float rel1 = (c1 - fcx) * 96.0f;
        s_pos[t]  = iy * 96 + ix;
        s_rel0[t] = rel0;
        s_rel1[t] = rel1;
        s_rc0[t]  = cell[q * 2 + 0] * 96.0f;
        s_rc1[t]  = cell[q * 2 + 1] * 96.0f;
        s_area[t] = fabsf(rel0 * rel1) + 1e-9f;
    }
    __syncthreads();

    // ---- layer 0 (vectorized): thread = 8 rows x 8 cols
    {
        const int cg = t & 31;                 // col chunk: cols cg*8 .. +7
        const int rg = t >> 5;                 // row group: rows rg*8 .. +7
        const float* wbase = w0 + 576 * 256 + cg * 8;
        float4 wa0 = *(const float4*)(wbase);
        float4 wa1 = *(const float4*)(wbase + 4);
        float4 wb0 = *(const float4*)(wbase + 256);
        float4 wb1 = *(const float4*)(wbase + 260);
        float4 wc0 = *(const float4*)(wbase + 512);
        float4 wc1 = *(const float4*)(wbase + 516);
        float4 wd0 = *(const float4*)(wbase + 768);
        float4 wd1 = *(const float4*)(wbase + 772);
        #pragma unroll
        for (int rr = 0; rr < 8; ++rr) {
            const int m = rg * 8 + rr;
            half8 qv = *(const half8*)&A0[s_pos[m] * 256 + cg * 8];
            float r0 = s_rel0[m], r1 = s_rel1[m], rc0 = s_rc0[m], rc1 = s_rc1[m];
            half8 o;
            float v;
            v = (float)qv[0]; v = fmaf(r0,wa0.x,v); v = fmaf(r1,wb0.x,v); v = fmaf(rc0,wc0.x,v); v = fmaf(rc1,wd0.x,v); o[0] = (_Float16)fmaxf(v,0.f);
            v = (float)qv[1]; v = fmaf(r0,wa0.y,v); v = fmaf(r1,wb0.y,v); v = fmaf(rc0,wc0.y,v); v = fmaf(rc1,wd0.y,v); o[1] = (_Float16)fmaxf(v,0.f);
            v = (float)qv[2]; v = fmaf(r0,wa0.z,v); v = fmaf(r1,wb0.z,v); v = fmaf(rc0,wc0.z,v); v = fmaf(rc1,wd0.z,v); o[2] = (_Float16)fmaxf(v,0.f);
            v = (float)qv[3]; v = fmaf(r0,wa0.w,v); v = fmaf(r1,wb0.w,v); v = fmaf(rc0,wc0.w,v); v = fmaf(rc1,wd0.w,v); o[3] = (_Float16)fmaxf(v,0.f);
            v = (float)qv[4]; v = fmaf(r0,wa1.x,v); v = fmaf(r1,wb1.x,v); v = fmaf(rc0,wc1.x,v); v = fmaf(rc1,wd1.x,v); o[4] = (_Float16)fmaxf(v,0.f);
            v = (float)qv[5]; v = fmaf(r0,wa1.y,v); v = fmaf(r1,wb1.y,v); v = fmaf(rc0,wc1.y,v); v = fmaf(rc1,wd1.y,v); o[5] = (_Float16)fmaxf(v,0.f);
            v = (float)qv[6]; v = fmaf(r0,wa1.z,v); v = fmaf(r1,wb1.z,v); v = fmaf(rc0,wc1.z,v); v = fmaf(rc1,wd1.z,v); o[6] = (_Float16)fmaxf(v,0.f);
            v = (float)qv[7]; v = fmaf(r0,wa1.w,v); v = fmaf(r1,wb1.w,v); v = fmaf(rc0,wc1.w,v); v = fmaf(rc1,wd1.w,v); o[7] = (_Float16)fmaxf(v,0.f);
            *(half8*)&h[m][cg * 8] = o;
        }
    }

    const int wave = t >> 6;
    const int lane = t & 63;
    const int wm = wave >> 2;
    const int wn = wave & 3;

    // prefetch layer-1 ks=0,1 B-frags before the barrier (in flight across it)
    half8 p0, p1, p2, p3, q0, q1, q2, q3;
    {
        const _Float16* bp0 = wf32 + (wn * 2) * 512 + lane * 8;
        const _Float16* bp1 = wf32 + (8 + wn * 2) * 512 + lane * 8;
        p0 = *(const half8*)bp0;
        p1 = *(const half8*)(bp0 + 512);
        p2 = *(const half8*)bp1;
        p3 = *(const half8*)(bp1 + 512);
    }
    BAR();

    hidden_layer32(h, wf32,             b1, wf32 + 65536,     false, p0,p1,p2,p3, q0,q1,q2,q3, wm, wn, lane);
    hidden_layer32(h, wf32 + 65536,     b2, wf32 + 2 * 65536, false, q0,q1,q2,q3, p0,p1,p2,p3, wm, wn, lane);
    hidden_layer32(h, wf32 + 2 * 65536, b3, wf4,              true,  p0,p1,p2,p3, q0,q1,q2,q3, wm, wn, lane);

    // ---- final layer 256 -> 3 via 16x16x32 MFMA; wave = 16-row tile
    {
        const int l15 = lane & 15;
        const int l4  = lane >> 4;
        f32x4 acc = (f32x4){0.f, 0.f, 0.f, 0.f};
        half8 a;
        a = *(const half8*)&h[wave * 16 + l15][0 * 32 + l4 * 8];
        acc = __builtin_amdgcn_mfma_f32_16x16x32_f16(a, q0, acc, 0, 0, 0);
        a = *(const half8*)&h[wave * 16 + l15][1 * 32 + l4 * 8];
        acc = __builtin_amdgcn_mfma_f32_16x16x32_f16(a, q1, acc, 0, 0, 0);
        a = *(const half8*)&h[wave * 16 + l15][2 * 32 + l4 * 8];
        acc = __builtin_amdgcn_mfma_f32_16x16x32_f16(a, q2, acc, 0, 0, 0);
        a = *(const half8*)&h[wave * 16 + l15][3 * 32 + l4 * 8];
        acc = __builtin_amdgcn_mfma_f32_16x16x32_f16(a, q3, acc, 0, 0, 0);
        #pragma unroll
        for (int ks = 4; ks < 8; ++ks) {
            a = *(const half8*)&h[wave * 16 + l15][ks * 32 + l4 * 8];
            half8 b = *(const half8*)&wf4[(ks * 64 + lane) * 8];
            acc = __builtin_amdgcn_mfma_f32_16x16x32_f16(a, b, acc, 0, 0, 0);
        }
        if (l15 < 3) {
            float bv = b4[l15];
            #pragma unroll
            for (int i = 0; i < 4; ++i)
                pred[wave * 16 + l4 * 4 + i][l15] = acc[i] + bv;
        }
    }
    BAR();

    // ---- local-ensemble combine (diagonal area swap), 32 queries per block
    if (t < 96) {
        int ql = t / 3;
        int o  = t - ql * 3;
        int mb = ql * 4;
        float a0 = s_area[mb + 0];
        float a1 = s_area[mb + 1];
        float a2 = s_area[mb + 2];
        float a3 = s_area[mb + 3];
        float tot = a0 + a1 + a2 + a3;
        float rv = pred[mb + 0][o] * a3 + pred[mb + 1][o] * a2 +
                   pred[mb + 2][o] * a1 + pred[mb + 3][o] * a0;
        out[(blk * 32 + ql) * 3 + o] = rv / tot;
    }
}

// ---------------------------------------------------------------------------
extern "C" void kernel_launch(void* const* d_in, const int* in_sizes, int n_in,
                              void* d_out, int out_size, void* d_ws, size_t ws_size,
                              hipStream_t stream)
{
    (void)in_sizes; (void)n_in; (void)out_size; (void)ws_size;
    const float* inp   = (const float*)d_in[0];
    const float* coord = (const float*)d_in[1];
    const float* cell  = (const float*)d_in[2];
    const float* enc_w = (const float*)d_in[3];
    const float* enc_b = (const float*)d_in[4];
    const float* w0 = (const float*)d_in[5];
    const float* b0 = (const float*)d_in[6];
    const float* w1 = (const float*)d_in[7];
    const float* b1 = (const float*)d_in[8];
    const float* w2 = (const float*)d_in[9];
    const float* b2 = (const float*)d_in[10];
    const float* w3 = (const float*)d_in[11];
    const float* b3 = (const float*)d_in[12];
    const float* w4 = (const float*)d_in[13];
    const float* b4 = (const float*)d_in[14];
    float* outp = (float*)d_out;

    char* ws = (char*)d_ws;
    _Float16* featT = (_Float16*)(ws + OFF_FEATT);
    _Float16* A0    = (_Float16*)(ws + OFF_A0);
    _Float16* wf32  = (_Float16*)(ws + OFF_WF32);
    _Float16* wf4   = (_Float16*)(ws + OFF_WF4);
    _Float16* wB    = (_Float16*)(ws + OFF_WB);

    setup_kernel<<<dim3(NB_FEAT + NB_PA + NB_PW4 + NB_PB), dim3(256), 0, stream>>>(
        inp, enc_w, enc_b, w0, w1, w2, w3, w4, featT, wf32, wf4, wB);
    a0_mfma<<<dim3(144), dim3(256), 0, stream>>>(featT, wB, b0, A0);
    fused_kernel<<<dim3(2048), dim3(512), 0, stream>>>(A0, coord, cell, w0,
                                                       b1, b2, b3, b4, wf32, wf4, outp);
}

// Round 5
// 291.879 us; speedup vs baseline: 1.0438x; 1.0174x over previous
//
#include <hip/hip_runtime.h>
#include <math.h>

#define NPOS 9216   // 96*96

using half8  = __attribute__((ext_vector_type(8))) _Float16;
using f32x4  = __attribute__((ext_vector_type(4))) float;
using f32x16 = __attribute__((ext_vector_type(16))) float;

// ---- workspace layout (byte offsets, all 16B aligned) ----
#define OFF_FEATT 0u         // 98*98*64 f16 = 1,229,312 B (zero-padded border)
#define OFF_A0    1229312u   // 9216*256 f16 = 4,718,592 B
#define OFF_WF32  5947904u   // 3*65536 f16 (hidden B-frags, 32x32x16)
#define OFF_WF4   6341120u   // 4096 f16 (w4 B-frags, 16x16x32, padded to 16 cols)
#define OFF_WB    6349312u   // 9*2*16*64*8 f16 (a0 B-frags, 16x16x32)

#define NB_FEAT 2401   // 9604 positions / 4 per block
#define NB_PA   768    // 3*65536 / 256
#define NB_PW4  16     // 4096 / 256
#define NB_PB   576    // 147456 / 256

// raw barrier: LDS-ordered, but does NOT drain vmcnt (prefetch stays in flight)
#define BAR() do { asm volatile("s_waitcnt lgkmcnt(0)" ::: "memory"); \
                   __builtin_amdgcn_s_barrier();                      \
                   asm volatile("" ::: "memory"); } while (0)

// ---------------------------------------------------------------------------
// Setup: (a) conv encoder -> zero-padded position-major f16 featT[98][98][64]
//        (b) pack w1/w2/w3 into 32x32x16 B-fragment order
//        (c) pack w4 into 16x16x32 B-fragment order (cols padded 3->16)
//        (d) pack w0's first 576 rows into 16x16x32 B-frags per unfold tap t9
// ---------------------------------------------------------------------------
__global__ __launch_bounds__(256) void setup_kernel(
    const float* __restrict__ inp, const float* __restrict__ enc_w,
    const float* __restrict__ enc_b, const float* __restrict__ w0,
    const float* __restrict__ w1, const float* __restrict__ w2,
    const float* __restrict__ w3, const float* __restrict__ w4,
    _Float16* __restrict__ featT, _Float16* __restrict__ wf32,
    _Float16* __restrict__ wf4, _Float16* __restrict__ wB)
{
    int blk = blockIdx.x;
    const int t = threadIdx.x;

    if (blk < NB_FEAT) {                       // conv -> featT (padded)
        int pp = blk * 4 + (t >> 6);           // 0..9603
        int c  = t & 63;
        int py = pp / 98, px = pp - py * 98;
        float acc = 0.0f;
        if (py >= 1 && py <= 96 && px >= 1 && px <= 96) {
            int y = py - 1, x = px - 1;
            acc = enc_b[c];
            #pragma unroll
            for (int cin = 0; cin < 3; ++cin) {
                #pragma unroll
                for (int ky = 0; ky < 3; ++ky) {
                    int yy = y + ky - 1;
                    if (yy < 0 || yy >= 96) continue;
                    #pragma unroll
                    for (int kx = 0; kx < 3; ++kx) {
                        int xx = x + kx - 1;
                        if (xx < 0 || xx >= 96) continue;
                        acc = fmaf(inp[cin * NPOS + yy * 96 + xx],
                                   enc_w[c * 27 + cin * 9 + ky * 3 + kx], acc);
                    }
                }
            }
        }
        featT[pp * 64 + c] = (_Float16)acc;
        return;
    }
    blk -= NB_FEAT;
    if (blk < NB_PA) {                         // hidden weights, 32x32x16 B-frag
        int idx = blk * 256 + t;               // 0..196607
        int l = idx >> 16;
        int r = idx & 65535;
        int j    = r & 7;
        int lane = (r >> 3) & 63;
        int nt32 = (r >> 9) & 7;
        int ks   = r >> 12;                    // 0..15
        int n = nt32 * 32 + (lane & 31);
        int k = ks * 16 + ((lane >> 5) << 3) + j;
        const float* W = (l == 0) ? w1 : (l == 1) ? w2 : w3;
        wf32[idx] = (_Float16)W[k * 256 + n];
        return;
    }
    blk -= NB_PA;
    if (blk < NB_PW4) {                        // w4, 16x16x32 B-frag
        int idx = blk * 256 + t;               // 0..4095
        int j    = idx & 7;
        int lane = (idx >> 3) & 63;
        int ks   = idx >> 9;                   // 0..7
        int n = lane & 15;
        int k = ks * 32 + ((lane >> 4) << 3) + j;
        wf4[idx] = (n < 3) ? (_Float16)w4[k * 3 + n] : (_Float16)0.0f;
        return;
    }
    blk -= NB_PW4;
    {                                          // w0 taps, 16x16x32 B-frag (K=64 per tap)
        int idx = blk * 256 + t;               // 0..147455
        int j    = idx & 7;
        int lane = (idx >> 3) & 63;
        int ntB  = (idx >> 9) & 15;
        int ks   = (idx >> 13) & 1;
        int t9   = idx >> 14;                  // 0..8
        int c = ks * 32 + ((lane >> 4) << 3) + j;
        int n = ntB * 16 + (lane & 15);
        wB[idx] = (_Float16)w0[(c * 9 + t9) * 256 + n];
    }
}

// ---------------------------------------------------------------------------
// a0 via MFMA: A0[pos][o] = b0[o] + sum_t9 featT(pos shifted by t9) @ w0-tap-t9
// ---------------------------------------------------------------------------
__global__ __launch_bounds__(256) void a0_mfma(const _Float16* __restrict__ featT,
                                               const _Float16* __restrict__ wB,
                                               const float* __restrict__ b0,
                                               _Float16* __restrict__ A0)
{
    const int lane = threadIdx.x & 63;
    const int tile = blockIdx.x * 4 + (threadIdx.x >> 6);   // 0..575
    const int l15  = lane & 15;
    const int l4   = lane >> 4;
    int r = tile * 16 + l15;
    int y = r / 96, x = r - y * 96;

    f32x4 acc[16];
    #pragma unroll
    for (int nt = 0; nt < 16; ++nt) acc[nt] = (f32x4){0.f, 0.f, 0.f, 0.f};

    #pragma unroll
    for (int t9 = 0; t9 < 9; ++t9) {
        int ki = t9 / 3, kj = t9 - ki * 3;
        const _Float16* ap = featT + ((y + ki) * 98 + (x + kj)) * 64 + l4 * 8;
        #pragma unroll
        for (int ks = 0; ks < 2; ++ks) {
            half8 a = *(const half8*)(ap + ks * 32);
            const _Float16* bp = wB + ((t9 * 2 + ks) * 16 * 64 + lane) * 8;
            #pragma unroll
            for (int nt = 0; nt < 16; ++nt) {
                half8 b = *(const half8*)(bp + nt * 512);
                acc[nt] = __builtin_amdgcn_mfma_f32_16x16x32_f16(a, b, acc[nt], 0, 0, 0);
            }
        }
    }
    int rb = tile * 16 + l4 * 4;
    #pragma unroll
    for (int nt = 0; nt < 16; ++nt) {
        float bb = b0[nt * 16 + l15];
        #pragma unroll
        for (int i = 0; i < 4; ++i)
            A0[(rb + i) * 256 + nt * 16 + l15] = (_Float16)(acc[nt][i] + bb);
    }
}

// ---------------------------------------------------------------------------
// Hidden layer on 32x32x16 MFMA, 64 rows, 4 waves (wave = 64-col tile wn).
// p0..p3 = this layer's ks=0,1 B-frags (preloaded). q0..q3 = next prefetch out.
// ---------------------------------------------------------------------------
__device__ __forceinline__ void hidden_layer32(
    _Float16 (*h)[264], const _Float16* __restrict__ W,
    const float* __restrict__ bias, const _Float16* __restrict__ Wpre,
    bool preIsFinal,
    half8 p0, half8 p1, half8 p2, half8 p3,
    half8& q0, half8& q1, half8& q2, half8& q3,
    int wn, int lane)
{
    const int l31 = lane & 31;
    const int l5  = lane >> 5;
    f32x16 a00 = {}, a01 = {}, a10 = {}, a11 = {};

    // ks = 0,1 from prefetched frags
    {
        half8 Av0 = *(const half8*)&h[l31][l5 * 8];
        half8 Av1 = *(const half8*)&h[32 + l31][l5 * 8];
        a00 = __builtin_amdgcn_mfma_f32_32x32x16_f16(Av0, p0, a00, 0, 0, 0);
        a01 = __builtin_amdgcn_mfma_f32_32x32x16_f16(Av0, p1, a01, 0, 0, 0);
        a10 = __builtin_amdgcn_mfma_f32_32x32x16_f16(Av1, p0, a10, 0, 0, 0);
        a11 = __builtin_amdgcn_mfma_f32_32x32x16_f16(Av1, p1, a11, 0, 0, 0);
        Av0 = *(const half8*)&h[l31][16 + l5 * 8];
        Av1 = *(const half8*)&h[32 + l31][16 + l5 * 8];
        a00 = __builtin_amdgcn_mfma_f32_32x32x16_f16(Av0, p2, a00, 0, 0, 0);
        a01 = __builtin_amdgcn_mfma_f32_32x32x16_f16(Av0, p3, a01, 0, 0, 0);
        a10 = __builtin_amdgcn_mfma_f32_32x32x16_f16(Av1, p2, a10, 0, 0, 0);
        a11 = __builtin_amdgcn_mfma_f32_32x32x16_f16(Av1, p3, a11, 0, 0, 0);
    }
    #pragma unroll
    for (int ks = 2; ks < 16; ++ks) {
        half8 Av0 = *(const half8*)&h[l31][ks * 16 + l5 * 8];
        half8 Av1 = *(const half8*)&h[32 + l31][ks * 16 + l5 * 8];
        const _Float16* bp = W + (ks * 8 + wn * 2) * 512 + lane * 8;
        half8 Bv0 = *(const half8*)bp;
        half8 Bv1 = *(const half8*)(bp + 512);
        a00 = __builtin_amdgcn_mfma_f32_32x32x16_f16(Av0, Bv0, a00, 0, 0, 0);
        a01 = __builtin_amdgcn_mfma_f32_32x32x16_f16(Av0, Bv1, a01, 0, 0, 0);
        a10 = __builtin_amdgcn_mfma_f32_32x32x16_f16(Av1, Bv0, a10, 0, 0, 0);
        a11 = __builtin_amdgcn_mfma_f32_32x32x16_f16(Av1, Bv1, a11, 0, 0, 0);
    }

    // prefetch next layer's ks=0,1 (or final w4 ks=0..3); stays in flight across BAR
    if (preIsFinal) {
        q0 = *(const half8*)&Wpre[(0 * 64 + lane) * 8];
        q1 = *(const half8*)&Wpre[(1 * 64 + lane) * 8];
        q2 = *(const half8*)&Wpre[(2 * 64 + lane) * 8];
        q3 = *(const half8*)&Wpre[(3 * 64 + lane) * 8];
    } else {
        const _Float16* bp0 = Wpre + (wn * 2) * 512 + lane * 8;
        const _Float16* bp1 = Wpre + (8 + wn * 2) * 512 + lane * 8;
        q0 = *(const half8*)bp0;
        q1 = *(const half8*)(bp0 + 512);
        q2 = *(const half8*)bp1;
        q3 = *(const half8*)(bp1 + 512);
    }

    BAR();   // all reads of h done before overwrite
    float bv0 = bias[wn * 64 + l31];
    float bv1 = bias[wn * 64 + 32 + l31];
    #pragma unroll
    for (int reg = 0; reg < 16; ++reg) {
        int rr = (reg & 3) + ((reg >> 2) << 3) + (l5 << 2);
        int c0 = wn * 64 + l31;
        h[rr][c0]           = (_Float16)fmaxf(a00[reg] + bv0, 0.0f);
        h[rr][c0 + 32]      = (_Float16)fmaxf(a01[reg] + bv1, 0.0f);
        h[rr + 32][c0]      = (_Float16)fmaxf(a10[reg] + bv0, 0.0f);
        h[rr + 32][c0 + 32] = (_Float16)fmaxf(a11[reg] + bv1, 0.0f);
    }
    BAR();   // h ready for next layer
}

__global__ __launch_bounds__(256, 4) void fused_kernel(
    const _Float16* __restrict__ A0, const float* __restrict__ coord,
    const float* __restrict__ cell, const float* __restrict__ w0,
    const float* __restrict__ b1, const float* __restrict__ b2,
    const float* __restrict__ b3, const float* __restrict__ b4,
    const _Float16* __restrict__ wf32, const _Float16* __restrict__ wf4,
    float* __restrict__ out)
{
    __shared__ _Float16 h[64][264];
    __shared__ float pred[64][4];
    __shared__ float s_rel0[64], s_rel1[64], s_rc0[64], s_rc1[64], s_area[64];
    __shared__ int   s_pos[64];

    const int t   = threadIdx.x;
    const int blk = blockIdx.x;

    if (t < 64) {
        int r = blk * 64 + t;
        int q = r >> 2;
        int j = r & 3;                         // (vx,vy): 0:(-,-) 1:(-,+) 2:(+,-) 3:(+,+)
        float vx = (j & 2) ? 1.0f : -1.0f;
        float vy = (j & 1) ? 1.0f : -1.0f;
        float c0 = coord[q * 2 + 0];
        float c1 = coord[q * 2 + 1];
        const float rr  = 1.0f / 96.0f;
        const float bnd = 1.0f - 1e-6f;
        float sc0 = fminf(fmaxf(fmaf(vx, rr, c0) + 1e-6f, -bnd), bnd);
        float sc1 = fminf(fmaxf(fmaf(vy, rr, c1) + 1e-6f, -bnd), bnd);
        float fy = (sc0 + 1.0f) * 48.0f - 0.5f;
        float fx = (sc1 + 1.0f) * 48.0f - 0.5f;
        int iy = (int)rintf(fy); iy = iy < 0 ? 0 : (iy > 95 ? 95 : iy);
        int ix = (int)rintf(fx); ix = ix < 0 ? 0 : (ix > 95 ? 95 : ix);
        float fcy = -1.0f + (2.0f * (float)iy + 1.0f) / 96.0f;
        float fcx = -1.0f + (2.0f * (float)ix + 1.0f) / 96.0f;
        float rel0 = (c0 - fcy) * 96.0f;
        float rel1 = (c1 - fcx) * 96.0f;
        s_pos[t]  = iy * 96 + ix;
        s_rel0[t] = rel0;
        s_rel1[t] = rel1;
        s_rc0[t]  = cell[q * 2 + 0] * 96.0f;
        s_rc1[t]  = cell[q * 2 + 1] * 96.0f;
        s_area[t] = fabsf(rel0 * rel1) + 1e-9f;
    }
    __syncthreads();

    // ---- layer 0 (vectorized): thread = 8 rows x 8 cols
    {
        const int cg = t & 31;                 // col chunk: cols cg*8 .. +7
        const int rg = t >> 5;                 // row group: rows rg*8 .. +7
        const float* wbase = w0 + 576 * 256 + cg * 8;
        float4 wa0 = *(const float4*)(wbase);
        float4 wa1 = *(const float4*)(wbase + 4);
        float4 wb0 = *(const float4*)(wbase + 256);
        float4 wb1 = *(const float4*)(wbase + 260);
        float4 wc0 = *(const float4*)(wbase + 512);
        float4 wc1 = *(const float4*)(wbase + 516);
        float4 wd0 = *(const float4*)(wbase + 768);
        float4 wd1 = *(const float4*)(wbase + 772);
        #pragma unroll
        for (int rr = 0; rr < 8; ++rr) {
            const int m = rg * 8 + rr;
            half8 qv = *(const half8*)&A0[s_pos[m] * 256 + cg * 8];
            float r0 = s_rel0[m], r1 = s_rel1[m], rc0 = s_rc0[m], rc1 = s_rc1[m];
            half8 o;
            float v;
            v = (float)qv[0]; v = fmaf(r0,wa0.x,v); v = fmaf(r1,wb0.x,v); v = fmaf(rc0,wc0.x,v); v = fmaf(rc1,wd0.x,v); o[0] = (_Float16)fmaxf(v,0.f);
            v = (float)qv[1]; v = fmaf(r0,wa0.y,v); v = fmaf(r1,wb0.y,v); v = fmaf(rc0,wc0.y,v); v = fmaf(rc1,wd0.y,v); o[1] = (_Float16)fmaxf(v,0.f);
            v = (float)qv[2]; v = fmaf(r0,wa0.z,v); v = fmaf(r1,wb0.z,v); v = fmaf(rc0,wc0.z,v); v = fmaf(rc1,wd0.z,v); o[2] = (_Float16)fmaxf(v,0.f);
            v = (float)qv[3]; v = fmaf(r0,wa0.w,v); v = fmaf(r1,wb0.w,v); v = fmaf(rc0,wc0.w,v); v = fmaf(rc1,wd0.w,v); o[3] = (_Float16)fmaxf(v,0.f);
            v = (float)qv[4]; v = fmaf(r0,wa1.x,v); v = fmaf(r1,wb1.x,v); v = fmaf(rc0,wc1.x,v); v = fmaf(rc1,wd1.x,v); o[4] = (_Float16)fmaxf(v,0.f);
            v = (float)qv[5]; v = fmaf(r0,wa1.y,v); v = fmaf(r1,wb1.y,v); v = fmaf(rc0,wc1.y,v); v = fmaf(rc1,wd1.y,v); o[5] = (_Float16)fmaxf(v,0.f);
            v = (float)qv[6]; v = fmaf(r0,wa1.z,v); v = fmaf(r1,wb1.z,v); v = fmaf(rc0,wc1.z,v); v = fmaf(rc1,wd1.z,v); o[6] = (_Float16)fmaxf(v,0.f);
            v = (float)qv[7]; v = fmaf(r0,wa1.w,v); v = fmaf(r1,wb1.w,v); v = fmaf(rc0,wc1.w,v); v = fmaf(rc1,wd1.w,v); o[7] = (_Float16)fmaxf(v,0.f);
            *(half8*)&h[m][cg * 8] = o;
        }
    }

    const int wave = t >> 6;
    const int lane = t & 63;
    const int wn   = wave;                     // 4 waves = 4 col tiles

    // prefetch layer-1 ks=0,1 B-frags before the barrier (in flight across it)
    half8 p0, p1, p2, p3, q0, q1, q2, q3;
    {
        const _Float16* bp0 = wf32 + (wn * 2) * 512 + lane * 8;
        const _Float16* bp1 = wf32 + (8 + wn * 2) * 512 + lane * 8;
        p0 = *(const half8*)bp0;
        p1 = *(const half8*)(bp0 + 512);
        p2 = *(const half8*)bp1;
        p3 = *(const half8*)(bp1 + 512);
    }
    BAR();

    hidden_layer32(h, wf32,             b1, wf32 + 65536,     false, p0,p1,p2,p3, q0,q1,q2,q3, wn, lane);
    hidden_layer32(h, wf32 + 65536,     b2, wf32 + 2 * 65536, false, q0,q1,q2,q3, p0,p1,p2,p3, wn, lane);
    hidden_layer32(h, wf32 + 2 * 65536, b3, wf4,              true,  p0,p1,p2,p3, q0,q1,q2,q3, wn, lane);

    // ---- final layer 256 -> 3 via 16x16x32 MFMA; wave = 16-row tile
    {
        const int l15 = lane & 15;
        const int l4  = lane >> 4;
        f32x4 acc = (f32x4){0.f, 0.f, 0.f, 0.f};
        half8 a;
        a = *(const half8*)&h[wave * 16 + l15][0 * 32 + l4 * 8];
        acc = __builtin_amdgcn_mfma_f32_16x16x32_f16(a, q0, acc, 0, 0, 0);
        a = *(const half8*)&h[wave * 16 + l15][1 * 32 + l4 * 8];
        acc = __builtin_amdgcn_mfma_f32_16x16x32_f16(a, q1, acc, 0, 0, 0);
        a = *(const half8*)&h[wave * 16 + l15][2 * 32 + l4 * 8];
        acc = __builtin_amdgcn_mfma_f32_16x16x32_f16(a, q2, acc, 0, 0, 0);
        a = *(const half8*)&h[wave * 16 + l15][3 * 32 + l4 * 8];
        acc = __builtin_amdgcn_mfma_f32_16x16x32_f16(a, q3, acc, 0, 0, 0);
        #pragma unroll
        for (int ks = 4; ks < 8; ++ks) {
            a = *(const half8*)&h[wave * 16 + l15][ks * 32 + l4 * 8];
            half8 b = *(const half8*)&wf4[(ks * 64 + lane) * 8];
            acc = __builtin_amdgcn_mfma_f32_16x16x32_f16(a, b, acc, 0, 0, 0);
        }
        if (l15 < 3) {
            float bv = b4[l15];
            #pragma unroll
            for (int i = 0; i < 4; ++i)
                pred[wave * 16 + l4 * 4 + i][l15] = acc[i] + bv;
        }
    }
    BAR();

    // ---- local-ensemble combine (diagonal area swap), 16 queries per block
    if (t < 48) {
        int ql = t / 3;
        int o  = t - ql * 3;
        int mb = ql * 4;
        float a0 = s_area[mb + 0];
        float a1 = s_area[mb + 1];
        float a2 = s_area[mb + 2];
        float a3 = s_area[mb + 3];
        float tot = a0 + a1 + a2 + a3;
        float rv = pred[mb + 0][o] * a3 + pred[mb + 1][o] * a2 +
                   pred[mb + 2][o] * a1 + pred[mb + 3][o] * a0;
        out[(blk * 16 + ql) * 3 + o] = rv / tot;
    }
}

// ---------------------------------------------------------------------------
extern "C" void kernel_launch(void* const* d_in, const int* in_sizes, int n_in,
                              void* d_out, int out_size, void* d_ws, size_t ws_size,
                              hipStream_t stream)
{
    (void)in_sizes; (void)n_in; (void)out_size; (void)ws_size;
    const float* inp   = (const float*)d_in[0];
    const float* coord = (const float*)d_in[1];
    const float* cell  = (const float*)d_in[2];
    const float* enc_w = (const float*)d_in[3];
    const float* enc_b = (const float*)d_in[4];
    const float* w0 = (const float*)d_in[5];
    const float* b0 = (const float*)d_in[6];
    const float* w1 = (const float*)d_in[7];
    const float* b1 = (const float*)d_in[8];
    const float* w2 = (const float*)d_in[9];
    const float* b2 = (const float*)d_in[10];
    const float* w3 = (const float*)d_in[11];
    const float* b3 = (const float*)d_in[12];
    const float* w4 = (const float*)d_in[13];
    const float* b4 = (const float*)d_in[14];
    float* outp = (float*)d_out;

    char* ws = (char*)d_ws;
    _Float16* featT = (_Float16*)(ws + OFF_FEATT);
    _Float16* A0    = (_Float16*)(ws + OFF_A0);
    _Float16* wf32  = (_Float16*)(ws + OFF_WF32);
    _Float16* wf4   = (_Float16*)(ws + OFF_WF4);
    _Float16* wB    = (_Float16*)(ws + OFF_WB);

    setup_kernel<<<dim3(NB_FEAT + NB_PA + NB_PW4 + NB_PB), dim3(256), 0, stream>>>(
        inp, enc_w, enc_b, w0, w1, w2, w3, w4, featT, wf32, wf4, wB);
    a0_mfma<<<dim3(144), dim3(256), 0, stream>>>(featT, wB, b0, A0);
    fused_kernel<<<dim3(4096), dim3(256), 0, stream>>>(A0, coord, cell, w0,
                                                       b1, b2, b3, b4, wf32, wf4, outp);
}

// Round 7
// 287.554 us; speedup vs baseline: 1.0595x; 1.0150x over previous
//
#include <hip/hip_runtime.h>
#include <math.h>

#define NPOS 9216   // 96*96

using half8  = __attribute__((ext_vector_type(8))) _Float16;
using f32x4  = __attribute__((ext_vector_type(4))) float;
using f32x16 = __attribute__((ext_vector_type(16))) float;

// ---- workspace layout (byte offsets, all 16B aligned) ----
#define OFF_FEATT 0u         // 98*98*64 f16 = 1,229,312 B (zero-padded border)
#define OFF_A0    1229312u   // 9216*256 f16 = 4,718,592 B
#define OFF_WF32  5947904u   // 3*65536 f16 (hidden B-frags, 32x32x16)
#define OFF_WF4   6341120u   // 4096 f16 (w4 B-frags, 16x16x32, padded to 16 cols)
#define OFF_WB    6349312u   // 9*2*16*64*8 f16 (a0 B-frags, 16x16x32)

#define NB_FEAT 2401   // 9604 positions / 4 per block
#define NB_PA   768    // 3*65536 / 256
#define NB_PW4  16     // 4096 / 256
#define NB_PB   576    // 147456 / 256

// raw barrier: LDS-ordered, but does NOT drain vmcnt (prefetch stays in flight)
#define BAR() do { asm volatile("s_waitcnt lgkmcnt(0)" ::: "memory"); \
                   __builtin_amdgcn_s_barrier();                      \
                   asm volatile("" ::: "memory"); } while (0)

// ---------------------------------------------------------------------------
// Setup: (a) conv encoder -> zero-padded position-major f16 featT[98][98][64]
//        (b) pack w1/w2/w3 into 32x32x16 B-fragment order
//        (c) pack w4 into 16x16x32 B-fragment order (cols padded 3->16)
//        (d) pack w0's first 576 rows into 16x16x32 B-frags per unfold tap t9
// ---------------------------------------------------------------------------
__global__ __launch_bounds__(256) void setup_kernel(
    const float* __restrict__ inp, const float* __restrict__ enc_w,
    const float* __restrict__ enc_b, const float* __restrict__ w0,
    const float* __restrict__ w1, const float* __restrict__ w2,
    const float* __restrict__ w3, const float* __restrict__ w4,
    _Float16* __restrict__ featT, _Float16* __restrict__ wf32,
    _Float16* __restrict__ wf4, _Float16* __restrict__ wB)
{
    int blk = blockIdx.x;
    const int t = threadIdx.x;

    if (blk < NB_FEAT) {                       // conv -> featT (padded)
        int pp = blk * 4 + (t >> 6);           // 0..9603
        int c  = t & 63;
        int py = pp / 98, px = pp - py * 98;
        float acc = 0.0f;
        if (py >= 1 && py <= 96 && px >= 1 && px <= 96) {
            int y = py - 1, x = px - 1;
            acc = enc_b[c];
            #pragma unroll
            for (int cin = 0; cin < 3; ++cin) {
                #pragma unroll
                for (int ky = 0; ky < 3; ++ky) {
                    int yy = y + ky - 1;
                    if (yy < 0 || yy >= 96) continue;
                    #pragma unroll
                    for (int kx = 0; kx < 3; ++kx) {
                        int xx = x + kx - 1;
                        if (xx < 0 || xx >= 96) continue;
                        acc = fmaf(inp[cin * NPOS + yy * 96 + xx],
                                   enc_w[c * 27 + cin * 9 + ky * 3 + kx], acc);
                    }
                }
            }
        }
        featT[pp * 64 + c] = (_Float16)acc;
        return;
    }
    blk -= NB_FEAT;
    if (blk < NB_PA) {                         // hidden weights, 32x32x16 B-frag
        int idx = blk * 256 + t;               // 0..196607
        int l = idx >> 16;
        int r = idx & 65535;
        int j    = r & 7;
        int lane = (r >> 3) & 63;
        int nt32 = (r >> 9) & 7;
        int ks   = r >> 12;                    // 0..15
        int n = nt32 * 32 + (lane & 31);
        int k = ks * 16 + ((lane >> 5) << 3) + j;
        const float* W = (l == 0) ? w1 : (l == 1) ? w2 : w3;
        wf32[idx] = (_Float16)W[k * 256 + n];
        return;
    }
    blk -= NB_PA;
    if (blk < NB_PW4) {                        // w4, 16x16x32 B-frag
        int idx = blk * 256 + t;               // 0..4095
        int j    = idx & 7;
        int lane = (idx >> 3) & 63;
        int ks   = idx >> 9;                   // 0..7
        int n = lane & 15;
        int k = ks * 32 + ((lane >> 4) << 3) + j;
        wf4[idx] = (n < 3) ? (_Float16)w4[k * 3 + n] : (_Float16)0.0f;
        return;
    }
    blk -= NB_PW4;
    {                                          // w0 taps, 16x16x32 B-frag (K=64 per tap)
        int idx = blk * 256 + t;               // 0..147455
        int j    = idx & 7;
        int lane = (idx >> 3) & 63;
        int ntB  = (idx >> 9) & 15;
        int ks   = (idx >> 13) & 1;
        int t9   = idx >> 14;                  // 0..8
        int c = ks * 32 + ((lane >> 4) << 3) + j;
        int n = ntB * 16 + (lane & 15);
        wB[idx] = (_Float16)w0[(c * 9 + t9) * 256 + n];
    }
}

// ---------------------------------------------------------------------------
// a0 via MFMA: A0[pos][o] = b0[o] + sum_t9 featT(pos shifted by t9) @ w0-tap-t9
// ---------------------------------------------------------------------------
__global__ __launch_bounds__(256) void a0_mfma(const _Float16* __restrict__ featT,
                                               const _Float16* __restrict__ wB,
                                               const float* __restrict__ b0,
                                               _Float16* __restrict__ A0)
{
    const int lane = threadIdx.x & 63;
    const int tile = blockIdx.x * 4 + (threadIdx.x >> 6);   // 0..575
    const int l15  = lane & 15;
    const int l4   = lane >> 4;
    int r = tile * 16 + l15;
    int y = r / 96, x = r - y * 96;

    f32x4 acc[16];
    #pragma unroll
    for (int nt = 0; nt < 16; ++nt) acc[nt] = (f32x4){0.f, 0.f, 0.f, 0.f};

    #pragma unroll
    for (int t9 = 0; t9 < 9; ++t9) {
        int ki = t9 / 3, kj = t9 - ki * 3;
        const _Float16* ap = featT + ((y + ki) * 98 + (x + kj)) * 64 + l4 * 8;
        #pragma unroll
        for (int ks = 0; ks < 2; ++ks) {
            half8 a = *(const half8*)(ap + ks * 32);
            const _Float16* bp = wB + ((t9 * 2 + ks) * 16 * 64 + lane) * 8;
            #pragma unroll
            for (int nt = 0; nt < 16; ++nt) {
                half8 b = *(const half8*)(bp + nt * 512);
                acc[nt] = __builtin_amdgcn_mfma_f32_16x16x32_f16(a, b, acc[nt], 0, 0, 0);
            }
        }
    }
    int rb = tile * 16 + l4 * 4;
    #pragma unroll
    for (int nt = 0; nt < 16; ++nt) {
        float bb = b0[nt * 16 + l15];
        #pragma unroll
        for (int i = 0; i < 4; ++i)
            A0[(rb + i) * 256 + nt * 16 + l15] = (_Float16)(acc[nt][i] + bb);
    }
}

// ---------------------------------------------------------------------------
// Hidden layer, 256-row block, 8 waves, wave = 128 rows x 64 cols (8 x 32x32
// tiles, 128 acc VGPRs). B-frags: ring buffer, prefetch distance 3 k-steps.
// p0..p5 = this layer's ks=0,1,2 B-frags. q0..q5 = next layer's (out).
// ---------------------------------------------------------------------------
__device__ __forceinline__ void hidden_layer_big(
    _Float16 (*h)[264],
    const _Float16* __restrict__ W, const float* __restrict__ bias,
    const _Float16* __restrict__ Wnext, const _Float16* __restrict__ wf4,
    bool nextIsFinal,
    half8 p0, half8 p1, half8 p2, half8 p3, half8 p4, half8 p5,
    half8& q0, half8& q1, half8& q2, half8& q3, half8& q4, half8& q5,
    int wm, int wn, int lane)
{
    const int l31 = lane & 31;
    const int l5  = lane >> 5;
    const int ra  = wm * 128 + l31;
    const _Float16* bbase = W + (wn * 2) * 512 + lane * 8;   // +ct*512, +ks*4096

    f32x16 acc[4][2];
    #pragma unroll
    for (int rt = 0; rt < 4; ++rt)
        #pragma unroll
        for (int ct = 0; ct < 2; ++ct)
            acc[rt][ct] = (f32x16){};

    half8 B[3][2];
    B[0][0] = p0; B[0][1] = p1;
    B[1][0] = p2; B[1][1] = p3;
    B[2][0] = p4; B[2][1] = p5;

    #pragma unroll
    for (int ks = 0; ks < 16; ++ks) {
        const int cs = ks % 3;
        half8 bu0 = B[cs][0];
        half8 bu1 = B[cs][1];
        if (ks <= 12) {                        // load ks+3 into freed slot
            B[cs][0] = *(const half8*)(bbase + (ks + 3) * 4096);
            B[cs][1] = *(const half8*)(bbase + (ks + 3) * 4096 + 512);
        } else {                               // ks=13,14,15: prefetch next layer ks=0,1,2
            const int nk = ks - 13;
            if (nextIsFinal) {
                half8 f0 = *(const half8*)&wf4[((2 * nk + 0) * 64 + lane) * 8];
                half8 f1 = *(const half8*)&wf4[((2 * nk + 1) * 64 + lane) * 8];
                if (nk == 0) { q0 = f0; q1 = f1; }
                else if (nk == 1) { q2 = f0; q3 = f1; }
                else { q4 = f0; q5 = f1; }
            } else {
                const _Float16* nb = Wnext + (nk * 8 + wn * 2) * 512 + lane * 8;
                half8 f0 = *(const half8*)nb;
                half8 f1 = *(const half8*)(nb + 512);
                if (nk == 0) { q0 = f0; q1 = f1; }
                else if (nk == 1) { q2 = f0; q3 = f1; }
                else { q4 = f0; q5 = f1; }
            }
        }
        half8 a0 = *(const half8*)&h[ra +  0][ks * 16 + l5 * 8];
        half8 a1 = *(const half8*)&h[ra + 32][ks * 16 + l5 * 8];
        half8 a2 = *(const half8*)&h[ra + 64][ks * 16 + l5 * 8];
        half8 a3 = *(const half8*)&h[ra + 96][ks * 16 + l5 * 8];
        acc[0][0] = __builtin_amdgcn_mfma_f32_32x32x16_f16(a0, bu0, acc[0][0], 0, 0, 0);
        acc[0][1] = __builtin_amdgcn_mfma_f32_32x32x16_f16(a0, bu1, acc[0][1], 0, 0, 0);
        acc[1][0] = __builtin_amdgcn_mfma_f32_32x32x16_f16(a1, bu0, acc[1][0], 0, 0, 0);
        acc[1][1] = __builtin_amdgcn_mfma_f32_32x32x16_f16(a1, bu1, acc[1][1], 0, 0, 0);
        acc[2][0] = __builtin_amdgcn_mfma_f32_32x32x16_f16(a2, bu0, acc[2][0], 0, 0, 0);
        acc[2][1] = __builtin_amdgcn_mfma_f32_32x32x16_f16(a2, bu1, acc[2][1], 0, 0, 0);
        acc[3][0] = __builtin_amdgcn_mfma_f32_32x32x16_f16(a3, bu0, acc[3][0], 0, 0, 0);
        acc[3][1] = __builtin_amdgcn_mfma_f32_32x32x16_f16(a3, bu1, acc[3][1], 0, 0, 0);
    }

    BAR();   // all reads of h done before overwrite
    float bv0 = bias[wn * 64 + l31];
    float bv1 = bias[wn * 64 + 32 + l31];
    #pragma unroll
    for (int rt = 0; rt < 4; ++rt) {
        #pragma unroll
        for (int reg = 0; reg < 16; ++reg) {
            int rr = wm * 128 + rt * 32 + (reg & 3) + ((reg >> 2) << 3) + (l5 << 2);
            int c0 = wn * 64 + l31;
            h[rr][c0]      = (_Float16)fmaxf(acc[rt][0][reg] + bv0, 0.0f);
            h[rr][c0 + 32] = (_Float16)fmaxf(acc[rt][1][reg] + bv1, 0.0f);
        }
    }
    BAR();   // h ready for next layer
}

__global__ __launch_bounds__(512, 2) void fused_kernel(
    const _Float16* __restrict__ A0, const float* __restrict__ coord,
    const float* __restrict__ cell, const float* __restrict__ w0,
    const float* __restrict__ b1, const float* __restrict__ b2,
    const float* __restrict__ b3, const float* __restrict__ b4,
    const _Float16* __restrict__ wf32, const _Float16* __restrict__ wf4,
    float* __restrict__ out)
{
    __shared__ _Float16 h[256][264];           // 135168 B
    __shared__ float pred[256][4];
    __shared__ float s_rel0[256], s_rel1[256], s_rc0[256], s_rc1[256], s_area[256];
    __shared__ int   s_pos[256];

    const int t    = threadIdx.x;
    const int blk  = blockIdx.x;
    const int wave = t >> 6;
    const int lane = t & 63;
    const int wm   = wave & 1;                 // row half (128 rows)
    const int wn   = wave >> 1;                // col quad (64 cols)

    // prefetch layer-1 ks=0,1,2 B-frags immediately (independent of LDS)
    half8 p0, p1, p2, p3, p4, p5, q0, q1, q2, q3, q4, q5;
    {
        const _Float16* bp = wf32 + (wn * 2) * 512 + lane * 8;
        p0 = *(const half8*)(bp);
        p1 = *(const half8*)(bp + 512);
        p2 = *(const half8*)(bp + 4096);
        p3 = *(const half8*)(bp + 4096 + 512);
        p4 = *(const half8*)(bp + 8192);
        p5 = *(const half8*)(bp + 8192 + 512);
    }

    if (t < 256) {
        int r = blk * 256 + t;
        int q = r >> 2;
        int j = r & 3;                         // (vx,vy): 0:(-,-) 1:(-,+) 2:(+,-) 3:(+,+)
        float vx = (j & 2) ? 1.0f : -1.0f;
        float vy = (j & 1) ? 1.0f : -1.0f;
        float c0 = coord[q * 2 + 0];
        float c1 = coord[q * 2 + 1];
        const float rr  = 1.0f / 96.0f;
        const float bnd = 1.0f - 1e-6f;
        float sc0 = fminf(fmaxf(fmaf(vx, rr, c0) + 1e-6f, -bnd), bnd);
        float sc1 = fminf(fmaxf(fmaf(vy, rr, c1) + 1e-6f, -bnd), bnd);
        float fy = (sc0 + 1.0f) * 48.0f - 0.5f;
        float fx = (sc1 + 1.0f) * 48.0f - 0.5f;
        int iy = (int)rintf(fy); iy = iy < 0 ? 0 : (iy > 95 ? 95 : iy);
        int ix = (int)rintf(fx); ix = ix < 0 ? 0 : (ix > 95 ? 95 : ix);
        float fcy = -1.0f + (2.0f * (float)iy + 1.0f) / 96.0f;
        float fcx = -1.0f + (2.0f * (float)ix + 1.0f) / 96.0f;
        float rel0 = (c0 - fcy) * 96.0f;
        float rel1 = (c1 - fcx) * 96.0f;
        s_pos[t]  = iy * 96 + ix;
        s_rel0[t] = rel0;
        s_rel1[t] = rel1;
        s_rc0[t]  = cell[q * 2 + 0] * 96.0f;
        s_rc1[t]  = cell[q * 2 + 1] * 96.0f;
        s_area[t] = fabsf(rel0 * rel1) + 1e-9f;
    }
    __syncthreads();

    // ---- layer 0 (vectorized): thread = 16 rows x 8 cols
    {
        const int cg = t & 31;                 // col chunk: cols cg*8 .. +7
        const int rg = t >> 5;                 // row group: rows rg*16 .. +15
        const float* wbase = w0 + 576 * 256 + cg * 8;
        float4 wa0 = *(const float4*)(wbase);
        float4 wa1 = *(const float4*)(wbase + 4);
        float4 wb0 = *(const float4*)(wbase + 256);
        float4 wb1 = *(const float4*)(wbase + 260);
        float4 wc0 = *(const float4*)(wbase + 512);
        float4 wc1 = *(const float4*)(wbase + 516);
        float4 wd0 = *(const float4*)(wbase + 768);
        float4 wd1 = *(const float4*)(wbase + 772);
        #pragma unroll
        for (int rr = 0; rr < 16; ++rr) {
            const int m = rg * 16 + rr;
            half8 qv = *(const half8*)&A0[s_pos[m] * 256 + cg * 8];
            float r0 = s_rel0[m], r1 = s_rel1[m], rc0 = s_rc0[m], rc1 = s_rc1[m];
            half8 o;
            float v;
            v = (float)qv[0]; v = fmaf(r0,wa0.x,v); v = fmaf(r1,wb0.x,v); v = fmaf(rc0,wc0.x,v); v = fmaf(rc1,wd0.x,v); o[0] = (_Float16)fmaxf(v,0.f);
            v = (float)qv[1]; v = fmaf(r0,wa0.y,v); v = fmaf(r1,wb0.y,v); v = fmaf(rc0,wc0.y,v); v = fmaf(rc1,wd0.y,v); o[1] = (_Float16)fmaxf(v,0.f);
            v = (float)qv[2]; v = fmaf(r0,wa0.z,v); v = fmaf(r1,wb0.z,v); v = fmaf(rc0,wc0.z,v); v = fmaf(rc1,wd0.z,v); o[2] = (_Float16)fmaxf(v,0.f);
            v = (float)qv[3]; v = fmaf(r0,wa0.w,v); v = fmaf(r1,wb0.w,v); v = fmaf(rc0,wc0.w,v); v = fmaf(rc1,wd0.w,v); o[3] = (_Float16)fmaxf(v,0.f);
            v = (float)qv[4]; v = fmaf(r0,wa1.x,v); v = fmaf(r1,wb1.x,v); v = fmaf(rc0,wc1.x,v); v = fmaf(rc1,wd1.x,v); o[4] = (_Float16)fmaxf(v,0.f);
            v = (float)qv[5]; v = fmaf(r0,wa1.y,v); v = fmaf(r1,wb1.y,v); v = fmaf(rc0,wc1.y,v); v = fmaf(rc1,wd1.y,v); o[5] = (_Float16)fmaxf(v,0.f);
            v = (float)qv[6]; v = fmaf(r0,wa1.z,v); v = fmaf(r1,wb1.z,v); v = fmaf(rc0,wc1.z,v); v = fmaf(rc1,wd1.z,v); o[6] = (_Float16)fmaxf(v,0.f);
            v = (float)qv[7]; v = fmaf(r0,wa1.w,v); v = fmaf(r1,wb1.w,v); v = fmaf(rc0,wc1.w,v); v = fmaf(rc1,wd1.w,v); o[7] = (_Float16)fmaxf(v,0.f);
            *(half8*)&h[m][cg * 8] = o;
        }
    }
    BAR();

    hidden_layer_big(h, wf32,             b1, wf32 + 65536,     wf4, false, p0,p1,p2,p3,p4,p5, q0,q1,q2,q3,q4,q5, wm, wn, lane);
    hidden_layer_big(h, wf32 + 65536,     b2, wf32 + 2 * 65536, wf4, false, q0,q1,q2,q3,q4,q5, p0,p1,p2,p3,p4,p5, wm, wn, lane);
    hidden_layer_big(h, wf32 + 2 * 65536, b3, (const _Float16*)0, wf4, true, p0,p1,p2,p3,p4,p5, q0,q1,q2,q3,q4,q5, wm, wn, lane);

    // ---- final layer 256 -> 3 via 16x16x32 MFMA; wave = 32-row strip (2 tiles)
    {
        const int l15 = lane & 15;
        const int l4  = lane >> 4;
        const int rowb = wave * 32;
        f32x4 acc0 = (f32x4){0.f, 0.f, 0.f, 0.f};
        f32x4 acc1 = (f32x4){0.f, 0.f, 0.f, 0.f};
        half8 b6 = *(const half8*)&wf4[(6 * 64 + lane) * 8];
        half8 b7 = *(const half8*)&wf4[(7 * 64 + lane) * 8];
        half8 bf[8] = {q0, q1, q2, q3, q4, q5, b6, b7};
        #pragma unroll
        for (int ks = 0; ks < 8; ++ks) {
            half8 a0 = *(const half8*)&h[rowb + l15][ks * 32 + l4 * 8];
            half8 a1 = *(const half8*)&h[rowb + 16 + l15][ks * 32 + l4 * 8];
            acc0 = __builtin_amdgcn_mfma_f32_16x16x32_f16(a0, bf[ks], acc0, 0, 0, 0);
            acc1 = __builtin_amdgcn_mfma_f32_16x16x32_f16(a1, bf[ks], acc1, 0, 0, 0);
        }
        if (l15 < 3) {
            float bv = b4[l15];
            #pragma unroll
            for (int i = 0; i < 4; ++i) {
                pred[rowb + l4 * 4 + i][l15]      = acc0[i] + bv;
                pred[rowb + 16 + l4 * 4 + i][l15] = acc1[i] + bv;
            }
        }
    }
    BAR();

    // ---- local-ensemble combine (diagonal area swap), 64 queries per block
    if (t < 192) {
        int ql = t / 3;
        int o  = t - ql * 3;
        int mb = ql * 4;
        float a0 = s_area[mb + 0];
        float a1 = s_area[mb + 1];
        float a2 = s_area[mb + 2];
        float a3 = s_area[mb + 3];
        float tot = a0 + a1 + a2 + a3;
        float rv = pred[mb + 0][o] * a3 + pred[mb + 1][o] * a2 +
                   pred[mb + 2][o] * a1 + pred[mb + 3][o] * a0;
        out[(blk * 64 + ql) * 3 + o] = rv / tot;
    }
}

// ---------------------------------------------------------------------------
extern "C" void kernel_launch(void* const* d_in, const int* in_sizes, int n_in,
                              void* d_out, int out_size, void* d_ws, size_t ws_size,
                              hipStream_t stream)
{
    (void)in_sizes; (void)n_in; (void)out_size; (void)ws_size;
    const float* inp   = (const float*)d_in[0];
    const float* coord = (const float*)d_in[1];
    const float* cell  = (const float*)d_in[2];
    const float* enc_w = (const float*)d_in[3];
    const float* enc_b = (const float*)d_in[4];
    const float* w0 = (const float*)d_in[5];
    const float* b0 = (const float*)d_in[6];
    const float* w1 = (const float*)d_in[7];
    const float* b1 = (const float*)d_in[8];
    const float* w2 = (const float*)d_in[9];
    const float* b2 = (const float*)d_in[10];
    const float* w3 = (const float*)d_in[11];
    const float* b3 = (const float*)d_in[12];
    const float* w4 = (const float*)d_in[13];
    const float* b4 = (const float*)d_in[14];
    float* outp = (float*)d_out;

    char* ws = (char*)d_ws;
    _Float16* featT = (_Float16*)(ws + OFF_FEATT);
    _Float16* A0    = (_Float16*)(ws + OFF_A0);
    _Float16* wf32  = (_Float16*)(ws + OFF_WF32);
    _Float16* wf4   = (_Float16*)(ws + OFF_WF4);
    _Float16* wB    = (_Float16*)(ws + OFF_WB);

    setup_kernel<<<dim3(NB_FEAT + NB_PA + NB_PW4 + NB_PB), dim3(256), 0, stream>>>(
        inp, enc_w, enc_b, w0, w1, w2, w3, w4, featT, wf32, wf4, wB);
    a0_mfma<<<dim3(144), dim3(256), 0, stream>>>(featT, wB, b0, A0);
    fused_kernel<<<dim3(1024), dim3(512), 0, stream>>>(A0, coord, cell, w0,
                                                       b1, b2, b3, b4, wf32, wf4, outp);
}